// Round 10
// baseline (11307.182 us; speedup 1.0000x reference)
//
#include <hip/hip_runtime.h>
#include <hip/hip_fp16.h>

#define B_ 256
#define T_ 512
#define D_ 128
#define H_ 2048
#define C_ 128
#define BSTRIDE 2052   // byte stride 4104 ≡ 8 (mod 128): conflict-free b128 LDS reads (r6-proven)
#define NCH 16         // staging chunks per (xcd,rowblock): 16 chunks x 4 rows (16 KB)
#define POLL_CAP 512   // bounded staging wait (~0.16 ms) -> fallback to direct-h path

// ws byte offsets
#define WS_H0  (0u)
#define WS_H1  (1u << 20)
#define WS_S0  (2u << 20)
#define WS_S1  (3u << 20)
#define WS_CNT (4u << 20)
#define NZERO  33792   // u32 words zeroed at WS_CNT: 1024 cnt + 16384 grab + 16384 done

typedef _Float16 half8 __attribute__((ext_vector_type(8)));
typedef float floatx4 __attribute__((ext_vector_type(4)));

// h storage is K-permuted (r7-proven): within each 32-col block, storage 2j<-col j, 2j+1<-col j+16.
//   sigma(s)   = (s & ~31) + ((s & 31) >> 1) + ((s & 1) << 4)
//   sigma^-1(k)= (k & ~31) | ((k & 15) << 1) | ((k >> 4) & 1)

// IF$-coherent loads (sc0 sc1): read the device coherence point (r7-proven).
__device__ __forceinline__ half8 llc_load16(const _Float16* p) {
    union { unsigned long long u[2]; half8 h; } v;
    const unsigned long long* q = (const unsigned long long*)p;
    v.u[0] = __hip_atomic_load(q,     __ATOMIC_RELAXED, __HIP_MEMORY_SCOPE_AGENT);
    v.u[1] = __hip_atomic_load(q + 1, __ATOMIC_RELAXED, __HIP_MEMORY_SCOPE_AGENT);
    return v.h;
}

__device__ __forceinline__ int xcc_id() {
    int x;
    asm volatile("s_getreg_b32 %0, hwreg(HW_REG_XCC_ID)" : "=s"(x));
    return x & 7;
}

// ---- h0 (permuted) = tanh(W_hx[x[:,0]] + b_h); zero all counters ----
__global__ void init_h(const int* __restrict__ x, const float* __restrict__ W_hx,
                       const float* __restrict__ b_h, char* __restrict__ ws) {
    int idx = blockIdx.x * blockDim.x + threadIdx.x;   // over B_*H_
    unsigned* ctr = (unsigned*)(ws + WS_CNT);
    if (idx < NZERO) ctr[idx] = 0;
    _Float16* h0 = (_Float16*)(ws + WS_H0);
    int b = idx >> 11, s = idx & (H_ - 1);
    int j = (s & ~31) + ((s & 31) >> 1) + ((s & 1) << 4);
    int xv = x[b * T_];
    h0[idx] = (_Float16)tanhf(W_hx[(size_t)xv * H_ + j] + b_h[j]);
}

// direct-h (fallback) A-load: IF$ ping-pong (r7-proven)
#define LOAD_BLK(dst, blk)                                                  \
    _Pragma("unroll") for (int u = 0; u < 8; ++u)                           \
        dst[u] = llc_load16(ap + ((blk) * 8 + u) * 32);

// staged A-load: sc0 (L1-bypass, local-L2-hit) inline asm
#define AL(dst, blk) { const _Float16* _ab = ap + (blk) * 256;              \
    _Pragma("unroll") for (int u = 0; u < 8; ++u)                           \
        asm volatile("global_load_dwordx4 %0, %1, off offset:%2 sc0"        \
                     : "=v"(dst[u]) : "v"(_ab), "i"(u * 64)); }

#define VWAIT(n)                                                            \
    asm volatile("s_waitcnt vmcnt(" #n ")" ::: "memory");                   \
    __builtin_amdgcn_sched_barrier(0);

#define COMP_BLK(src, blk)                                                  \
    _Pragma("unroll") for (int u = 0; u < 8; ++u) {                         \
        half8 b0v = *(const half8*)(bp0 + ((blk) * 8 + u) * 32);            \
        half8 b1v = *(const half8*)(bp1 + ((blk) * 8 + u) * 32);            \
        acc0 = __builtin_amdgcn_mfma_f32_16x16x32_f16(src[u], b0v, acc0, 0, 0, 0); \
        acc1 = __builtin_amdgcn_mfma_f32_16x16x32_f16(src[u], b1v, acc1, 0, 0, 0); \
    }

// per-(xcd,rowblock) staging of the group's own 64 h-rows: steal 16 chunks of 4 rows.
// Bounded waits; returns false on timeout (caller uses direct-h fallback). Stagers ==
// consumers of the region, so ANY WG->XCD distribution is self-consistent (G16-safe).
__device__ __forceinline__ bool stage_rb(const _Float16* hb, _Float16* sg,
                                         unsigned* grabp, unsigned* donep,
                                         int tid, int rbase_rows, int* s_tmp) {
    for (int iter = 0; iter < NCH + 2; ++iter) {
        if (tid == 0) {
            unsigned c = __hip_atomic_fetch_add(grabp, 1u, __ATOMIC_RELAXED,
                                                __HIP_MEMORY_SCOPE_AGENT);
            *s_tmp = (c < NCH) ? (int)c : -1;
        }
        __syncthreads();
        int c = *s_tmp;
        __syncthreads();
        if (c < 0) break;
        const size_t base = (size_t)(rbase_rows + c * 4) * H_ + tid * 8;
        half8 v0 = llc_load16(hb + base);
        half8 v1 = llc_load16(hb + base + H_);
        half8 v2 = llc_load16(hb + base + 2 * H_);
        half8 v3 = llc_load16(hb + base + 3 * H_);
        *(half8*)(sg + base)          = v0;   // normal stores -> dirty LOCAL L2
        *(half8*)(sg + base + H_)     = v1;
        *(half8*)(sg + base + 2 * H_) = v2;
        *(half8*)(sg + base + 3 * H_) = v3;
        __syncthreads();                      // vmcnt drain: chunk committed to L2
        if (tid == 0)
            __hip_atomic_fetch_add(donep, 1u, __ATOMIC_RELAXED, __HIP_MEMORY_SCOPE_AGENT);
    }
    if (tid == 0) {
        unsigned d = 0;
        int p = 0;
        while ((d = __hip_atomic_load(donep, __ATOMIC_RELAXED, __HIP_MEMORY_SCOPE_AGENT))
                   < (unsigned)NCH && p < POLL_CAP) { __builtin_amdgcn_s_sleep(4); ++p; }
        *s_tmp = (d >= (unsigned)NCH) ? 1 : 0;
    }
    __syncthreads();
    bool ok = (*s_tmp != 0);
    __syncthreads();
    return ok;
}

// ---- recurrence: 256 WGs (1/CU) x 256 thr; WG tile 64(M) x 32(N); W_hh^T slice in LDS ----
__global__ __launch_bounds__(256, 1)
void rnn_steps(const float* __restrict__ W_hh, char* __restrict__ ws,
               const int* __restrict__ x, const float* __restrict__ W_hx,
               const float* __restrict__ b_h) {
    extern __shared__ _Float16 bs[];   // [32 cols][BSTRIDE storage-k]
    __shared__ int s_tmp;
    _Float16* h0   = (_Float16*)(ws + WS_H0);
    _Float16* h1   = (_Float16*)(ws + WS_H1);
    _Float16* stg0 = (_Float16*)(ws + WS_S0);
    _Float16* stg1 = (_Float16*)(ws + WS_S1);
    unsigned* cnt  = (unsigned*)(ws + WS_CNT);
    unsigned* grab = cnt + 1024;
    unsigned* done = grab + 16384;

    const int bid = blockIdx.x;
    const int grp = bid & 7;
    const int g   = bid >> 3;
    const int colblock = grp * 8 + (g & 7);  // 0..63
    const int rowblock = g >> 3;             // 0..3
    const int nb  = colblock * 32;
    const int tid = threadIdx.x;
    const int myxcd = xcc_id();
    const int slotbase = ((myxcd << 2) | rowblock) * T_;   // staging slot group
    const int rbrows = rowblock * 64;        // this group's 64 h-rows

    // one-time: load + convert + transpose W_hh slice into LDS, K in storage order
    {
        const int c  = (tid & 7) * 4;
        const int kr = tid >> 3;
        for (int k = kr; k < H_; k += 32) {
            int s = (k & ~31) | ((k & 15) << 1) | ((k >> 4) & 1);   // sigma^-1(k)
            const float4 wv = *(const float4*)(W_hh + (size_t)k * H_ + nb + c);
            bs[(c + 0) * BSTRIDE + s] = (_Float16)wv.x;
            bs[(c + 1) * BSTRIDE + s] = (_Float16)wv.y;
            bs[(c + 2) * BSTRIDE + s] = (_Float16)wv.z;
            bs[(c + 3) * BSTRIDE + s] = (_Float16)wv.w;
        }
    }
    __syncthreads();

    const int w    = tid >> 6;
    const int l    = tid & 63;
    const int l15  = l & 15;
    const int kl   = (l >> 4) << 3;
    const int rbase  = rbrows + w * 16;
    const int arow   = rbase + l15;
    const int r0     = rbase + ((l >> 4) << 2);
    const _Float16* bp0 = bs + l15 * BSTRIDE + kl;
    const _Float16* bp1 = bs + (16 + l15) * BSTRIDE + kl;
    const int c0 = nb + l15;
    const float bh0 = b_h[c0], bh1 = b_h[c0 + 16];

    unsigned* mycnt = cnt + rowblock * 64;   // rowblock arrival counter (r7-proven barrier)

    // prologue: stage h_0 (slot 0)
    bool stgok = stage_rb(h0, stg0, grab + slotbase, done + slotbase, tid, rbrows, &s_tmp);

    for (int t = 1; t < T_; ++t) {
        const _Float16* __restrict__ hcd = (t & 1) ? h0 : h1;     // h_{t-1} direct (IF$)
        const _Float16* __restrict__ sgc = (t & 1) ? stg0 : stg1; // h_{t-1} staged (local L2)
        _Float16* __restrict__ hn        = (t & 1) ? h1 : h0;     // h_t publish target
        _Float16* __restrict__ sgn       = (t & 1) ? stg1 : stg0; // h_t staging target

        // epilogue-gather prefetch (warm L1/L2; nothing invalidates them)
        int   xv[4];
        float wx0[4], wx1[4];
#pragma unroll
        for (int jj = 0; jj < 4; ++jj) xv[jj] = x[(r0 + jj) * T_ + t];
#pragma unroll
        for (int jj = 0; jj < 4; ++jj) {
            wx0[jj] = W_hx[(size_t)xv[jj] * H_ + c0];
            wx1[jj] = W_hx[(size_t)xv[jj] * H_ + c0 + 16];
        }
        asm volatile("" ::: "memory");   // pin prefetch vmem above the counted pipeline

        floatx4 acc0 = {0.f, 0.f, 0.f, 0.f}, acc1 = {0.f, 0.f, 0.f, 0.f};
        half8 aA[8], aB[8];
        if (stgok) {
            // staged path: sc0 loads from local L2, counted-vmcnt 2-block pipeline
            const _Float16* ap = sgc + (size_t)arow * H_ + kl;
            AL(aA, 0); AL(aB, 1);
            VWAIT(8);  COMP_BLK(aA, 0);
            AL(aA, 2); VWAIT(8); COMP_BLK(aB, 1);
            AL(aB, 3); VWAIT(8); COMP_BLK(aA, 2);
            AL(aA, 4); VWAIT(8); COMP_BLK(aB, 3);
            AL(aB, 5); VWAIT(8); COMP_BLK(aA, 4);
            AL(aA, 6); VWAIT(8); COMP_BLK(aB, 5);
            AL(aB, 7); VWAIT(8); COMP_BLK(aA, 6);
            VWAIT(0);  COMP_BLK(aB, 7);
        } else {
            // fallback path: r7-proven IF$ ping-pong, always correct
            const _Float16* ap = hcd + (size_t)arow * H_ + kl;
            LOAD_BLK(aA, 0);
#pragma unroll
            for (int sb = 0; sb < 4; ++sb) {
                LOAD_BLK(aB, 2 * sb + 1);
                COMP_BLK(aA, 2 * sb);
                if (sb < 3) { LOAD_BLK(aA, 2 * sb + 2); }
                COMP_BLK(aB, 2 * sb + 1);
            }
        }

        // publish h_t: packed u32 atomic swaps at the IF$ (r7-proven), batched drain
        unsigned o[4];
#pragma unroll
        for (int jj = 0; jj < 4; ++jj) {
            float z0 = acc0[jj] + wx0[jj] + bh0;
            float z1 = acc1[jj] + wx1[jj] + bh1;
            _Float16 p0 = (_Float16)tanhf(z0), p1 = (_Float16)tanhf(z1);
            unsigned pv = ((unsigned)__builtin_bit_cast(unsigned short, p1) << 16)
                        |  (unsigned)__builtin_bit_cast(unsigned short, p0);
            unsigned* dstp = (unsigned*)(hn + (size_t)(r0 + jj) * H_ + nb + 2 * l15);
            o[jj] = __hip_atomic_exchange(dstp, pv, __ATOMIC_RELAXED,
                                          __HIP_MEMORY_SCOPE_AGENT);
        }
        asm volatile("" :: "v"(o[0]), "v"(o[1]), "v"(o[2]), "v"(o[3]));

        // per-rowblock monotonic barrier (r7-proven verbatim)
        __syncthreads();
        if (tid == 0) {
            __builtin_amdgcn_fence(__ATOMIC_RELEASE, "workgroup");
            __hip_atomic_fetch_add(mycnt, 1u, __ATOMIC_RELAXED, __HIP_MEMORY_SCOPE_AGENT);
            while (__hip_atomic_load(mycnt, __ATOMIC_RELAXED, __HIP_MEMORY_SCOPE_AGENT)
                   < (unsigned)(64 * t))
                __builtin_amdgcn_s_sleep(2);
            __builtin_amdgcn_fence(__ATOMIC_ACQUIRE, "workgroup");
        }
        __syncthreads();

        // stage h_t (own rows only; gated by the barrier just passed); bounded
        stgok = stage_rb(hn, sgn, grab + slotbase + t, done + slotbase + t, tid, rbrows, &s_tmp);
    }
}

// ---- out[b,c] = h[b,:] @ W_ph + b_p (fp32); h in permuted storage order ----
__global__ void final_proj(const char* __restrict__ ws, const float* __restrict__ W_ph,
                           const float* __restrict__ b_p, float* __restrict__ out) {
    __shared__ float part[C_];
    const _Float16* h = (const _Float16*)(ws + WS_H1);   // h after t=511 (odd)
    const int b  = blockIdx.x;
    const int c  = threadIdx.x & (C_ - 1);
    const int hh = threadIdx.x >> 7;
    const int j0 = hh * (H_ / 2);
    float acc = 0.f;
#pragma unroll 4
    for (int s = j0; s < j0 + H_ / 2; ++s) {
        int k = (s & ~31) + ((s & 31) >> 1) + ((s & 1) << 4);   // sigma(s)
        acc = fmaf((float)h[(size_t)b * H_ + s], W_ph[k * C_ + c], acc);
    }
    if (hh) part[c] = acc;
    __syncthreads();
    if (!hh) out[b * C_ + c] = acc + part[c] + b_p[c];
}

extern "C" void kernel_launch(void* const* d_in, const int* in_sizes, int n_in,
                              void* d_out, int out_size, void* d_ws, size_t ws_size,
                              hipStream_t stream) {
    const int*   x    = (const int*)d_in[0];
    const float* W_hx = (const float*)d_in[1];
    const float* W_hh = (const float*)d_in[2];
    const float* W_ph = (const float*)d_in[3];
    const float* b_h  = (const float*)d_in[4];
    const float* b_p  = (const float*)d_in[5];
    float* out = (float*)d_out;
    char* ws = (char*)d_ws;

    init_h<<<(B_ * H_) / 256, 256, 0, stream>>>(x, W_hx, b_h, ws);

    const int smem = 32 * BSTRIDE * 2;   // 131328 B dynamic LDS
    (void)hipFuncSetAttribute((const void*)rnn_steps,
                              hipFuncAttributeMaxDynamicSharedMemorySize, smem);

    const float* whh = W_hh; char* pws = ws;
    const int* px = x; const float* pwhx = W_hx; const float* pbh = b_h;
    void* args[] = {(void*)&whh, (void*)&pws, (void*)&px, (void*)&pwhx, (void*)&pbh};
    hipError_t e = hipLaunchCooperativeKernel((void*)rnn_steps, dim3(256), dim3(256),
                                              args, smem, stream);
    if (e != hipSuccess) {
        rnn_steps<<<dim3(256), dim3(256), smem, stream>>>(whh, pws, px, pwhx, pbh);
    }

    final_proj<<<B_, 256, 0, stream>>>(ws, W_ph, b_p, out);
}

// Round 11
// 10151.519 us; speedup vs baseline: 1.1138x; 1.1138x over previous
//
#include <hip/hip_runtime.h>
#include <hip/hip_fp16.h>

#define B_ 256
#define T_ 512
#define D_ 128
#define H_ 2048
#define C_ 128
#define BSTRIDE 2052   // byte stride 4104 ≡ 8 (mod 128): conflict-free b128 LDS reads (r6-proven)
#define GUARD_CAP 65536

// ws byte offsets
#define WS_H0  (0u)
#define WS_H1  (1u << 20)
#define WS_CNT (2u << 20)

typedef _Float16 half8 __attribute__((ext_vector_type(8)));
typedef float floatx4 __attribute__((ext_vector_type(4)));

// h storage is K-permuted (r7-proven): within each 32-col block, storage 2j<-col j, 2j+1<-col j+16.
//   sigma(s)   = (s & ~31) + ((s & 31) >> 1) + ((s & 1) << 4)
//   sigma^-1(k)= (k & ~31) | ((k & 15) << 1) | ((k >> 4) & 1)

// IF$-coherent loads (sc0 sc1): read the device coherence point (r7-proven).
__device__ __forceinline__ half8 llc_load16(const _Float16* p) {
    union { unsigned long long u[2]; half8 h; } v;
    const unsigned long long* q = (const unsigned long long*)p;
    v.u[0] = __hip_atomic_load(q,     __ATOMIC_RELAXED, __HIP_MEMORY_SCOPE_AGENT);
    v.u[1] = __hip_atomic_load(q + 1, __ATOMIC_RELAXED, __HIP_MEMORY_SCOPE_AGENT);
    return v.h;
}

// ---- h0 (permuted) = tanh(W_hx[x[:,0]] + b_h); zero the flag words ----
__global__ void init_h(const int* __restrict__ x, const float* __restrict__ W_hx,
                       const float* __restrict__ b_h, char* __restrict__ ws) {
    int idx = blockIdx.x * blockDim.x + threadIdx.x;   // over B_*H_
    unsigned* ctr = (unsigned*)(ws + WS_CNT);
    if (idx < 1024) ctr[idx] = 0;
    _Float16* h0 = (_Float16*)(ws + WS_H0);
    int b = idx >> 11, s = idx & (H_ - 1);
    int j = (s & ~31) + ((s & 31) >> 1) + ((s & 1) << 4);
    int xv = x[b * T_];
    h0[idx] = (_Float16)tanhf(W_hx[(size_t)xv * H_ + j] + b_h[j]);
}

// r7-proven IF$ ping-pong K-loop pieces (fast path)
#define LOAD_BLK(dst, blk)                                                  \
    _Pragma("unroll") for (int u = 0; u < 8; ++u)                           \
        dst[u] = llc_load16(ap + ((blk) * 8 + u) * 32);

#define COMP_BLK(src, blk)                                                  \
    _Pragma("unroll") for (int u = 0; u < 8; ++u) {                         \
        half8 b0v = *(const half8*)(bp0 + ((blk) * 8 + u) * 32);            \
        half8 b1v = *(const half8*)(bp1 + ((blk) * 8 + u) * 32);            \
        acc0 = __builtin_amdgcn_mfma_f32_16x16x32_f16(src[u], b0v, acc0, 0, 0, 0); \
        acc1 = __builtin_amdgcn_mfma_f32_16x16x32_f16(src[u], b1v, acc1, 0, 0, 0); \
    }

// ---- recurrence: 256 WGs (1/CU) x 256 thr; WG tile 64(M) x 32(N); W_hh^T slice in LDS ----
// NO barrier. Per-WG flag[rb*64+cb] = number of steps published (r7 publish + flag bump).
// Consumers poll their rowblock's 64 flags (one coalesced load + ballot) and consume
// K-slices in ready-order: fast path when all 64 ready (common), batch-of-8 otherwise.
// Safety: WG publishes h(t) only after consuming all h(t-1) slices (flags>=t-1 observed),
// which implies the whole cohort finished reading h(t-2) -> double buffer suffices.
__global__ __launch_bounds__(256, 1)
void rnn_steps(const float* __restrict__ W_hh, char* __restrict__ ws,
               const int* __restrict__ x, const float* __restrict__ W_hx,
               const float* __restrict__ b_h) {
    extern __shared__ _Float16 bs[];   // [32 cols][BSTRIDE storage-k]
    _Float16* h0   = (_Float16*)(ws + WS_H0);
    _Float16* h1   = (_Float16*)(ws + WS_H1);
    unsigned* flags = (unsigned*)(ws + WS_CNT);

    const int bid = blockIdx.x;
    const int grp = bid & 7;
    const int g   = bid >> 3;
    const int colblock = grp * 8 + (g & 7);  // 0..63
    const int rowblock = g >> 3;             // 0..3
    const int nb  = colblock * 32;
    const int tid = threadIdx.x;

    // one-time: load + convert + transpose W_hh slice into LDS, K in storage order
    {
        const int c  = (tid & 7) * 4;
        const int kr = tid >> 3;
        for (int k = kr; k < H_; k += 32) {
            int s = (k & ~31) | ((k & 15) << 1) | ((k >> 4) & 1);   // sigma^-1(k)
            const float4 wv = *(const float4*)(W_hh + (size_t)k * H_ + nb + c);
            bs[(c + 0) * BSTRIDE + s] = (_Float16)wv.x;
            bs[(c + 1) * BSTRIDE + s] = (_Float16)wv.y;
            bs[(c + 2) * BSTRIDE + s] = (_Float16)wv.z;
            bs[(c + 3) * BSTRIDE + s] = (_Float16)wv.w;
        }
    }
    __syncthreads();

    const int w    = tid >> 6;
    const int l    = tid & 63;
    const int l15  = l & 15;
    const int kl   = (l >> 4) << 3;
    const int rbase  = rowblock * 64 + w * 16;
    const int arow   = rbase + l15;
    const int r0     = rbase + ((l >> 4) << 2);
    const _Float16* bp0 = bs + l15 * BSTRIDE + kl;
    const _Float16* bp1 = bs + (16 + l15) * BSTRIDE + kl;
    const int c0 = nb + l15;
    const float bh0 = b_h[c0], bh1 = b_h[c0 + 16];

    const unsigned* grpflags = flags + rowblock * 64;   // 64 producer flags (256B, coalesced)
    unsigned* myflag = flags + rowblock * 64 + colblock;

    for (int t = 1; t < T_; ++t) {
        const _Float16* __restrict__ hc = (t & 1) ? h0 : h1;  // h(t-1)
        _Float16* __restrict__ hn       = (t & 1) ? h1 : h0;  // h(t)

        // epilogue-gather prefetch (warm L1/L2)
        int   xv[4];
        float wx0[4], wx1[4];
#pragma unroll
        for (int jj = 0; jj < 4; ++jj) xv[jj] = x[(r0 + jj) * T_ + t];
#pragma unroll
        for (int jj = 0; jj < 4; ++jj) {
            wx0[jj] = W_hx[(size_t)xv[jj] * H_ + c0];
            wx1[jj] = W_hx[(size_t)xv[jj] * H_ + c0 + 16];
        }

        const _Float16* ap = hc + (size_t)arow * H_ + kl;
        floatx4 acc0 = {0.f, 0.f, 0.f, 0.f}, acc1 = {0.f, 0.f, 0.f, 0.f};
        const unsigned need = (unsigned)(t - 1);

        unsigned fv = __hip_atomic_load(grpflags + l, __ATOMIC_RELAXED,
                                        __HIP_MEMORY_SCOPE_AGENT);
        unsigned long long ready = __ballot(fv >= need);

        if (ready == ~0ull) {
            // fast path (common): all slices ready -> static pipelined loop (r7-proven)
            half8 aA[8], aB[8];
            LOAD_BLK(aA, 0);
#pragma unroll
            for (int sb = 0; sb < 4; ++sb) {
                LOAD_BLK(aB, 2 * sb + 1);
                COMP_BLK(aA, 2 * sb);
                if (sb < 3) { LOAD_BLK(aA, 2 * sb + 2); }
                COMP_BLK(aB, 2 * sb + 1);
            }
        } else {
            // slow path: consume ready slices in batches of 8 while stragglers finish
            unsigned long long done = 0;
            int guard = 0;
            while (done != ~0ull) {
                unsigned long long todo = ready & ~done;
                if (__popcll(todo) >= 8 || guard > GUARD_CAP) {
                    if (guard > GUARD_CAP) todo = ~done;   // escape: terminate, absmax flags it
                    int cc[8];
                    unsigned long long bm = 0;
#pragma unroll
                    for (int u = 0; u < 8; ++u) {
                        int c = (int)__builtin_ctzll(todo);
                        todo &= todo - 1;
                        cc[u] = c;
                        bm |= (1ull << c);
                    }
                    half8 av[8];
#pragma unroll
                    for (int u = 0; u < 8; ++u) av[u] = llc_load16(ap + cc[u] * 32);
#pragma unroll
                    for (int u = 0; u < 8; ++u) {
                        half8 b0v = *(const half8*)(bp0 + cc[u] * 32);
                        half8 b1v = *(const half8*)(bp1 + cc[u] * 32);
                        acc0 = __builtin_amdgcn_mfma_f32_16x16x32_f16(av[u], b0v, acc0, 0, 0, 0);
                        acc1 = __builtin_amdgcn_mfma_f32_16x16x32_f16(av[u], b1v, acc1, 0, 0, 0);
                    }
                    done |= bm;
                } else {
                    __builtin_amdgcn_s_sleep(1);
                    ++guard;
                }
                if (done != ~0ull) {
                    fv = __hip_atomic_load(grpflags + l, __ATOMIC_RELAXED,
                                           __HIP_MEMORY_SCOPE_AGENT);
                    ready = __ballot(fv >= need);
                }
            }
        }

        // publish h(t): packed u32 atomic swaps at the IF$ (r7-proven), batched drain
        unsigned o[4];
#pragma unroll
        for (int jj = 0; jj < 4; ++jj) {
            float z0 = acc0[jj] + wx0[jj] + bh0;
            float z1 = acc1[jj] + wx1[jj] + bh1;
            _Float16 p0 = (_Float16)tanhf(z0), p1 = (_Float16)tanhf(z1);
            unsigned pv = ((unsigned)__builtin_bit_cast(unsigned short, p1) << 16)
                        |  (unsigned)__builtin_bit_cast(unsigned short, p0);
            unsigned* dstp = (unsigned*)(hn + (size_t)(r0 + jj) * H_ + nb + 2 * l15);
            o[jj] = __hip_atomic_exchange(dstp, pv, __ATOMIC_RELAXED,
                                          __HIP_MEMORY_SCOPE_AGENT);
        }
        asm volatile("" :: "v"(o[0]), "v"(o[1]), "v"(o[2]), "v"(o[3]));

        // flag bump replaces the barrier: swaps drained (syncthreads) -> flag -> proceed
        __syncthreads();
        if (tid == 0) {
            __builtin_amdgcn_fence(__ATOMIC_RELEASE, "workgroup");   // ordering only
            __hip_atomic_fetch_add(myflag, 1u, __ATOMIC_RELAXED, __HIP_MEMORY_SCOPE_AGENT);
        }
        // NO wait here — next step's poll gates on data readiness.
    }
}

// ---- out[b,c] = h[b,:] @ W_ph + b_p (fp32); h in permuted storage order ----
__global__ void final_proj(const char* __restrict__ ws, const float* __restrict__ W_ph,
                           const float* __restrict__ b_p, float* __restrict__ out) {
    __shared__ float part[C_];
    const _Float16* h = (const _Float16*)(ws + WS_H1);   // h after t=511 (odd)
    const int b  = blockIdx.x;
    const int c  = threadIdx.x & (C_ - 1);
    const int hh = threadIdx.x >> 7;
    const int j0 = hh * (H_ / 2);
    float acc = 0.f;
#pragma unroll 4
    for (int s = j0; s < j0 + H_ / 2; ++s) {
        int k = (s & ~31) + ((s & 31) >> 1) + ((s & 1) << 4);   // sigma(s)
        acc = fmaf((float)h[(size_t)b * H_ + s], W_ph[k * C_ + c], acc);
    }
    if (hh) part[c] = acc;
    __syncthreads();
    if (!hh) out[b * C_ + c] = acc + part[c] + b_p[c];
}

extern "C" void kernel_launch(void* const* d_in, const int* in_sizes, int n_in,
                              void* d_out, int out_size, void* d_ws, size_t ws_size,
                              hipStream_t stream) {
    const int*   x    = (const int*)d_in[0];
    const float* W_hx = (const float*)d_in[1];
    const float* W_hh = (const float*)d_in[2];
    const float* W_ph = (const float*)d_in[3];
    const float* b_h  = (const float*)d_in[4];
    const float* b_p  = (const float*)d_in[5];
    float* out = (float*)d_out;
    char* ws = (char*)d_ws;

    init_h<<<(B_ * H_) / 256, 256, 0, stream>>>(x, W_hx, b_h, ws);

    const int smem = 32 * BSTRIDE * 2;   // 131328 B dynamic LDS
    (void)hipFuncSetAttribute((const void*)rnn_steps,
                              hipFuncAttributeMaxDynamicSharedMemorySize, smem);

    const float* whh = W_hh; char* pws = ws;
    const int* px = x; const float* pwhx = W_hx; const float* pbh = b_h;
    void* args[] = {(void*)&whh, (void*)&pws, (void*)&px, (void*)&pwhx, (void*)&pbh};
    hipError_t e = hipLaunchCooperativeKernel((void*)rnn_steps, dim3(256), dim3(256),
                                              args, smem, stream);
    if (e != hipSuccess) {
        rnn_steps<<<dim3(256), dim3(256), smem, stream>>>(whh, pws, px, pwhx, pbh);
    }

    final_proj<<<B_, 256, 0, stream>>>(ws, W_ph, b_p, out);
}